// Round 17
// baseline (487.704 us; speedup 1.0000x reference)
//
#include <hip/hip_runtime.h>
#include <stdint.h>

// Problem dims (fixed)
#define BB 64
#define TT 32
#define EE 512
#define HH 512
#define VV 32000
#define G4 2048

typedef _Float16 f16x8 __attribute__((ext_vector_type(8)));
typedef float f32x4 __attribute__((ext_vector_type(4)));

__device__ __forceinline__ unsigned short f2h(float f) {
  return __builtin_bit_cast(unsigned short, (_Float16)f);   // RNE hw cvt
}
__device__ __forceinline__ void gload_lds16(const unsigned short* g, unsigned short* l) {
  __builtin_amdgcn_global_load_lds((const __attribute__((address_space(1))) void*)g,
                                   (__attribute__((address_space(3))) void*)l, 16, 0, 0);
}
__device__ __forceinline__ float sigm(float x) { return 1.f / (1.f + __expf(-x)); }
__device__ __forceinline__ float tanh_fast(float x) {
  return 1.f - 2.f / (__expf(2.f * x) + 1.f);   // stable at +-inf
}

// ---------------------------------------------------------------------------
// Kernel 1: gather+cast x inputs -> fp16 xseq[33][64][512].
// row r<64: xseq[0][r] = feat[r] (prime input); r=p*64+b (p>=1):
// xseq[p][b] = emb[cap[b*TT + (p-1)]]  (step p uses token t=p-1).
// ---------------------------------------------------------------------------
__global__ __launch_bounds__(128) void k_embed(const float* __restrict__ feat,
                                               const int* __restrict__ cap,
                                               const float* __restrict__ emb,
                                               unsigned short* __restrict__ xseq) {
  const int r = blockIdx.x;  // 0..2111
  const int t = threadIdx.x; // 128 thr x 4 f32
  const float* src;
  if (r < BB) {
    src = feat + (size_t)r * EE;
  } else {
    int p = r >> 6, b = r & 63;
    src = emb + (size_t)cap[b * TT + (p - 1)] * EE;
  }
  float4 v = ((const float4*)src)[t];
  ushort4 o;
  o.x = f2h(v.x); o.y = f2h(v.y); o.z = f2h(v.z); o.w = f2h(v.w);
  ((ushort4*)(xseq + (size_t)r * EE))[t] = o;
}

// ---------------------------------------------------------------------------
// Fence-free device barrier for 64 co-resident blocks (r6/r15/r16-proven).
// ---------------------------------------------------------------------------
__device__ __forceinline__ void gridbar_nf(int* flags, int id) {
  asm volatile("s_waitcnt vmcnt(0)" ::: "memory");
  __syncthreads();
  if (threadIdx.x == 0)
    __hip_atomic_store(&flags[blockIdx.x], id, __ATOMIC_RELAXED, __HIP_MEMORY_SCOPE_AGENT);
  if (threadIdx.x < 64) {
    while (__hip_atomic_load(&flags[threadIdx.x], __ATOMIC_RELAXED, __HIP_MEMORY_SCOPE_AGENT) < id)
      __builtin_amdgcn_s_sleep(4);
  }
  __syncthreads();
}

// ---------------------------------------------------------------------------
// Kernel 2: persistent LSTM recurrence, K=1024 fused-input form.
// gates_s = [x_s ; h_{s-1}] @ [W_ih | W_hh].T + (b_ih + b_hh).
// 64 blocks x 512 thr (8 waves).  Block owns u0=bid*8 (8 u x 4 gates = 32
// W'-rows of K=1024 fp16 in 64KB LDS, 16B-chunk XOR swizzle).  Wave
// (nt=w&1, mt=w>>1): 32 fp16 MFMAs/step (16 x-half from xseq -- no sync
// dependence -- + 16 h-half from hseq[s-1]).  Gate combine via XOR-swizzled
// gate_buf; biases folded into 4 per-thread register constants; c in reg;
// h packed-u32 agent-atomic to hseq[s]; prime = x-half only (h=c=0).
// ---------------------------------------------------------------------------
__global__ __launch_bounds__(512) void k_rnn(const unsigned short* __restrict__ xseq,
                                             const float* __restrict__ Wih,
                                             const float* __restrict__ Whh,
                                             const float* __restrict__ bih,
                                             const float* __restrict__ bhh,
                                             char* hseq_base,
                                             int* __restrict__ flags) {
  __shared__ __align__(16) unsigned short W_lds[32 * 1024];  // fp16, 64 KB
  __shared__ float gate_buf[2048];                           // 8 KB
  unsigned short* hseq16 = (unsigned short*)hseq_base;
  unsigned int* hseq32 = (unsigned int*)hseq_base;

  const int tid = threadIdx.x;
  const int bid = blockIdx.x;
  const int u0 = bid * 8;
  const int l = tid & 63;
  const int w = tid >> 6;          // wave 0..7
  const int lr = l & 15;
  const int kc = l >> 4;           // 0..3
  const int nt = w & 1;            // n-tile (W'-row half: 0 = gates i,f; 1 = g,o)
  const int mt = w >> 1;           // m-tile (16-sample group)
  const int es = w * 8 + (l >> 3); // 0..63
  const int edu = l & 7;           // 0..7
  const int wrow = nt * 16 + lr;   // LDS W'-row this lane reads

  // ---- stage [W_ih | W_hh] (f32 -> fp16) into LDS, chunk-XOR swizzled ----
  {
    int row = tid >> 4;            // 0..31  (= g*8 + du)
    int sub = tid & 15;
    int g = row >> 3, du = row & 7;
    const float* pih = Wih + (size_t)(g * 512 + u0 + du) * EE;
    const float* phh = Whh + (size_t)(g * 512 + u0 + du) * HH;
#pragma unroll
    for (int c0 = 0; c0 < 8; ++c0) {
      int c = sub * 8 + c0;        // 16B-chunk index 0..127 (8 f32 -> 8 fp16)
      const float* src = (c < 64) ? (pih + c * 8) : (phh + (c - 64) * 8);
      float4 va = *(const float4*)src;
      float4 vb = *(const float4*)(src + 4);
      __align__(16) unsigned short t8[8];
      t8[0] = f2h(va.x); t8[1] = f2h(va.y); t8[2] = f2h(va.z); t8[3] = f2h(va.w);
      t8[4] = f2h(vb.x); t8[5] = f2h(vb.y); t8[6] = f2h(vb.z); t8[7] = f2h(vb.w);
      *(int4*)&W_lds[row * 1024 + ((c ^ (row & 7)) * 8)] = *(const int4*)t8;
    }
  }

  // ---- per-thread bias constants (step-invariant) ----
  float bsum[4];
#pragma unroll
  for (int g = 0; g < 4; ++g) {
    int n = g * 512 + u0 + edu;
    bsum[g] = bih[n] + bhh[n];
  }
  __syncthreads();   // W_lds staged before prime MFMA

  const char* wbase = (const char*)W_lds + wrow * 2048;

  // ---- prime step (p=0): gates = x0 @ W_ih.T + b  (h = c = 0) ----
  float c_reg;
  {
    f32x4 acc = {0.f, 0.f, 0.f, 0.f};
    const unsigned short* xb = xseq + (size_t)(mt * 16 + lr) * EE + kc * 8;
#pragma unroll
    for (int kk = 0; kk < 16; ++kk) {
      uint4 xq = *(const uint4*)(xb + kk * 32);
      int4 wq = *(const int4*)(wbase + (((kk * 4 + kc) ^ (wrow & 7)) * 16));
      acc = __builtin_amdgcn_mfma_f32_16x16x32_f16(
          __builtin_bit_cast(f16x8, xq), __builtin_bit_cast(f16x8, wq), acc, 0, 0, 0);
    }
    {
      int g = nt * 2 + (lr >> 3);
      int du = lr & 7;
#pragma unroll
      for (int j = 0; j < 4; ++j) {
        int ss = mt * 16 + kc * 4 + j;
        gate_buf[g * 512 + du * 64 + (ss ^ (du << 3))] = acc[j];
      }
    }
    __syncthreads();
    {
      float gi = gate_buf[0 * 512 + edu * 64 + (es ^ (edu << 3))] + bsum[0];
      float gg = gate_buf[2 * 512 + edu * 64 + (es ^ (edu << 3))] + bsum[2];
      float go = gate_buf[3 * 512 + edu * 64 + (es ^ (edu << 3))] + bsum[3];
      float cn = sigm(gi) * tanh_fast(gg);
      float hn = sigm(go) * tanh_fast(cn);
      c_reg = cn;
      unsigned int hb = f2h(hn);
      unsigned int other = (unsigned int)__shfl_xor((int)hb, 1);
      if (!(l & 1))
        __hip_atomic_store(&hseq32[(size_t)es * 256 + bid * 4 + (edu >> 1)],
                           hb | (other << 16), __ATOMIC_RELAXED, __HIP_MEMORY_SCOPE_AGENT);
    }
  }
  gridbar_nf(flags, 1);

  // ---- 32 recurrent steps ----
  for (int s = 1; s <= TT; ++s) {
    const unsigned short* xb = xseq + (size_t)s * (BB * HH) + (size_t)(mt * 16 + lr) * EE + kc * 8;
    const unsigned short* hb2 = hseq16 + (size_t)(s - 1) * (BB * HH) + (size_t)(mt * 16 + lr) * HH + kc * 8;

    f32x4 acca = {0.f, 0.f, 0.f, 0.f};
    f32x4 accb = {0.f, 0.f, 0.f, 0.f};
#pragma unroll
    for (int kk = 0; kk < 16; ++kk) {
      uint4 xq = *(const uint4*)(xb + kk * 32);
      int4 wq = *(const int4*)(wbase + (((kk * 4 + kc) ^ (wrow & 7)) * 16));
      acca = __builtin_amdgcn_mfma_f32_16x16x32_f16(
          __builtin_bit_cast(f16x8, xq), __builtin_bit_cast(f16x8, wq), acca, 0, 0, 0);
    }
#pragma unroll
    for (int kk = 16; kk < 32; ++kk) {
      uint4 hq = *(const uint4*)(hb2 + (kk - 16) * 32);
      int4 wq = *(const int4*)(wbase + (((kk * 4 + kc) ^ (wrow & 7)) * 16));
      accb = __builtin_amdgcn_mfma_f32_16x16x32_f16(
          __builtin_bit_cast(f16x8, hq), __builtin_bit_cast(f16x8, wq), accb, 0, 0, 0);
    }
    f32x4 acc;
#pragma unroll
    for (int j = 0; j < 4; ++j) acc[j] = acca[j] + accb[j];

    // gate partials -> LDS (XOR-swizzled on sample index)
    {
      int g = nt * 2 + (lr >> 3);
      int du = lr & 7;
#pragma unroll
      for (int j = 0; j < 4; ++j) {
        int ss = mt * 16 + kc * 4 + j;
        gate_buf[g * 512 + du * 64 + (ss ^ (du << 3))] = acc[j];
      }
    }
    __syncthreads();

    // epilogue: one (es, edu) update per thread
    {
      float gi = gate_buf[0 * 512 + edu * 64 + (es ^ (edu << 3))] + bsum[0];
      float gf = gate_buf[1 * 512 + edu * 64 + (es ^ (edu << 3))] + bsum[1];
      float gg = gate_buf[2 * 512 + edu * 64 + (es ^ (edu << 3))] + bsum[2];
      float go = gate_buf[3 * 512 + edu * 64 + (es ^ (edu << 3))] + bsum[3];
      float cn = sigm(gf) * c_reg + sigm(gi) * tanh_fast(gg);
      float hn = sigm(go) * tanh_fast(cn);
      c_reg = cn;
      unsigned int hb = f2h(hn);
      unsigned int other = (unsigned int)__shfl_xor((int)hb, 1);
      if (!(l & 1))
        __hip_atomic_store(&hseq32[(size_t)s * 16384 + es * 256 + bid * 4 + (edu >> 1)],
                           hb | (other << 16), __ATOMIC_RELAXED, __HIP_MEMORY_SCOPE_AGENT);
    }

    if (s < TT) gridbar_nf(flags, s + 1);
  }
  // dispatch-end writeback publishes hseq to k_gemm_out (r12-r16 precedent)
}

// ---------------------------------------------------------------------------
// Kernel 3: Out = hseq[1..32] @ W_out.T + b_out   [fp16 MFMA, f32 out]
// (verbatim r16 — double-buffered h staging, W slice in registers.)
// ---------------------------------------------------------------------------
__global__ __launch_bounds__(512) void k_gemm_out(const unsigned short* __restrict__ hseq,
                                                  const float* __restrict__ Wout,
                                                  const float* __restrict__ bout,
                                                  float* __restrict__ out) {
  __shared__ __align__(16) unsigned short As[2][BB * HH];   // 2 x 64 KB
  const int tid = threadIdx.x;
  const int l = tid & 63;
  const int w = tid >> 6;
  const int n00 = blockIdx.x * 128;
  const int bcol = w * 16 + (l >> 4) * 4;
  const float4 bo0 = *(const float4*)(bout + n00 + bcol);

  // preload W_out slice f32 -> f16 fragments in registers (once)
  const int vr0 = n00 + w * 16 + (l & 15);
  const int kb = (l >> 4) * 8;
  uint4 w0r[16];
#pragma unroll
  for (int kt = 0; kt < 16; ++kt) {
    const float* p = Wout + (size_t)vr0 * HH + kt * 32 + kb;
    float4 a = *(const float4*)p;
    float4 b = *(const float4*)(p + 4);
    __align__(16) unsigned short t8[8];
    t8[0] = f2h(a.x); t8[1] = f2h(a.y); t8[2] = f2h(a.z); t8[3] = f2h(a.w);
    t8[4] = f2h(b.x); t8[5] = f2h(b.y); t8[6] = f2h(b.z); t8[7] = f2h(b.w);
    w0r[kt] = *(const uint4*)t8;
  }

  // stage step 1 into As[0]
  const unsigned short* hs1 = hseq + (size_t)1 * (BB * HH);
#pragma unroll
  for (int it = 0; it < 8; ++it) {
    int ci = it * 512 + tid;
    int row = ci >> 6, cd = ci & 63;
    gload_lds16(hs1 + (size_t)row * HH + (cd ^ (row & 7)) * 8, As[0] + ci * 8);
  }

  int cur = 0;
  for (int s = 1; s <= TT; ++s) {
    asm volatile("s_waitcnt vmcnt(0)" ::: "memory");   // stage of As[cur] done
    __syncthreads();                                   // + prev reads of As[cur] done

    if (s < TT) {
      const unsigned short* hs = hseq + (size_t)(s + 1) * (BB * HH);
#pragma unroll
      for (int it = 0; it < 8; ++it) {
        int ci = it * 512 + tid;
        int row = ci >> 6, cd = ci & 63;
        gload_lds16(hs + (size_t)row * HH + (cd ^ (row & 7)) * 8, As[cur ^ 1] + ci * 8);
      }
    }

    const unsigned short* Ab = As[cur];
    f32x4 acc0[4];
#pragma unroll
    for (int m = 0; m < 4; ++m) acc0[m] = (f32x4){0.f, 0.f, 0.f, 0.f};
#pragma unroll
    for (int m = 0; m < 4; ++m) {
      int row = m * 16 + (l & 15);
#pragma unroll
      for (int kt = 0; kt < 16; ++kt) {
        int c = kt * 4 + (l >> 4);
        f16x8 af = *(const f16x8*)&Ab[row * HH + (c ^ (row & 7)) * 8];
        // mfma(W, h): W-rows -> row-field (out col); h-rows -> col (out row)
        acc0[m] = __builtin_amdgcn_mfma_f32_16x16x32_f16(
            __builtin_bit_cast(f16x8, w0r[kt]), af, acc0[m], 0, 0, 0);
      }
    }
#pragma unroll
    for (int m = 0; m < 4; ++m) {
      int b = m * 16 + (l & 15);
      float* orow = out + ((size_t)(b * TT + (s - 1))) * VV + n00 + bcol;
      float4 v;
      v.x = acc0[m][0] + bo0.x;
      v.y = acc0[m][1] + bo0.y;
      v.z = acc0[m][2] + bo0.z;
      v.w = acc0[m][3] + bo0.w;
      *(float4*)orow = v;
    }
    cur ^= 1;
  }
}

// ---------------------------------------------------------------------------
extern "C" void kernel_launch(void* const* d_in, const int* in_sizes, int n_in,
                              void* d_out, int out_size, void* d_ws, size_t ws_size,
                              hipStream_t stream) {
  const float* feat = (const float*)d_in[0];
  const int* cap = (const int*)d_in[1];
  // d_in[2] = seq_len (constant 32)
  const float* emb = (const float*)d_in[3];
  const float* Wih = (const float*)d_in[4];
  const float* Whh = (const float*)d_in[5];
  const float* bih = (const float*)d_in[6];
  const float* bhh = (const float*)d_in[7];
  const float* Wout = (const float*)d_in[8];
  const float* bout = (const float*)d_in[9];
  float* out = (float*)d_out;

  char* ws = (char*)d_ws;
  unsigned short* xseq = (unsigned short*)ws;                 //  2,162,688 (33 x 64 x 512 fp16)
  char* hseq = ws + 2162688;                                  //  2,162,688
  int* flags = (int*)(ws + 4325376);                          //      4,096

  hipMemsetAsync(flags, 0, 4096, stream);
  k_embed<<<dim3(2112), dim3(128), 0, stream>>>(feat, cap, emb, xseq);
  k_rnn<<<dim3(64), dim3(512), 0, stream>>>(xseq, Wih, Whh, bih, bhh, hseq, flags);
  k_gemm_out<<<dim3(250), dim3(512), 0, stream>>>((const unsigned short*)hseq, Wout, bout, out);
}

// Round 18
// 418.321 us; speedup vs baseline: 1.1659x; 1.1659x over previous
//
#include <hip/hip_runtime.h>
#include <stdint.h>

// Problem dims (fixed)
#define BB 64
#define TT 32
#define EE 512
#define HH 512
#define VV 32000
#define G4 2048

typedef _Float16 f16x8 __attribute__((ext_vector_type(8)));
typedef float f32x4 __attribute__((ext_vector_type(4)));

__device__ __forceinline__ unsigned short f2h(float f) {
  return __builtin_bit_cast(unsigned short, (_Float16)f);   // RNE hw cvt
}
__device__ __forceinline__ void gload_lds16(const unsigned short* g, unsigned short* l) {
  __builtin_amdgcn_global_load_lds((const __attribute__((address_space(1))) void*)g,
                                   (__attribute__((address_space(3))) void*)l, 16, 0, 0);
}
__device__ __forceinline__ float sigm(float x) { return 1.f / (1.f + __expf(-x)); }
__device__ __forceinline__ float tanh_fast(float x) {
  return 1.f - 2.f / (__expf(2.f * x) + 1.f);   // stable at +-inf
}

// ---------------------------------------------------------------------------
// Kernel 1: gather+cast x inputs -> fp16 xseq[33][64][512].  (verbatim r17)
// ---------------------------------------------------------------------------
__global__ __launch_bounds__(128) void k_embed(const float* __restrict__ feat,
                                               const int* __restrict__ cap,
                                               const float* __restrict__ emb,
                                               unsigned short* __restrict__ xseq) {
  const int r = blockIdx.x;  // 0..2111
  const int t = threadIdx.x; // 128 thr x 4 f32
  const float* src;
  if (r < BB) {
    src = feat + (size_t)r * EE;
  } else {
    int p = r >> 6, b = r & 63;
    src = emb + (size_t)cap[b * TT + (p - 1)] * EE;
  }
  float4 v = ((const float4*)src)[t];
  ushort4 o;
  o.x = f2h(v.x); o.y = f2h(v.y); o.z = f2h(v.z); o.w = f2h(v.w);
  ((ushort4*)(xseq + (size_t)r * EE))[t] = o;
}

// ---------------------------------------------------------------------------
// Kernel 2: persistent LSTM recurrence, K=1024 fused-input form with the
// x-half MFMAs HOISTED into the barrier window.
// gates_s = [x_s ; h_{s-1}] @ [W_ih | W_hh].T + (b_ih + b_hh).
// 64 blocks x 512 thr.  Per step: post-barrier = 16 h-half MFMAs only
// (r16's proven cost); x-half of step s+1 computed between arrive(s+1) and
// wait(s+1) — dead time while peers finish.  Barrier = r15/16's proven
// arrive/wait (vmcnt drain + agent-atomic flag store; 64-line poll).
// ---------------------------------------------------------------------------
__global__ __launch_bounds__(512) void k_rnn(const unsigned short* __restrict__ xseq,
                                             const float* __restrict__ Wih,
                                             const float* __restrict__ Whh,
                                             const float* __restrict__ bih,
                                             const float* __restrict__ bhh,
                                             char* hseq_base,
                                             int* __restrict__ flags) {
  __shared__ __align__(16) unsigned short W_lds[32 * 1024];  // fp16, 64 KB
  __shared__ float gate_buf[2048];                           // 8 KB
  unsigned short* hseq16 = (unsigned short*)hseq_base;
  unsigned int* hseq32 = (unsigned int*)hseq_base;

  const int tid = threadIdx.x;
  const int bid = blockIdx.x;
  const int u0 = bid * 8;
  const int l = tid & 63;
  const int w = tid >> 6;          // wave 0..7
  const int lr = l & 15;
  const int kc = l >> 4;           // 0..3
  const int nt = w & 1;            // n-tile (W'-row half: 0 = gates i,f; 1 = g,o)
  const int mt = w >> 1;           // m-tile (16-sample group)
  const int es = w * 8 + (l >> 3); // 0..63
  const int edu = l & 7;           // 0..7
  const int wrow = nt * 16 + lr;   // LDS W'-row this lane reads

  // ---- stage [W_ih | W_hh] (f32 -> fp16) into LDS, chunk-XOR swizzled ----
  {
    int row = tid >> 4;            // 0..31  (= g*8 + du)
    int sub = tid & 15;
    int g = row >> 3, du = row & 7;
    const float* pih = Wih + (size_t)(g * 512 + u0 + du) * EE;
    const float* phh = Whh + (size_t)(g * 512 + u0 + du) * HH;
#pragma unroll
    for (int c0 = 0; c0 < 8; ++c0) {
      int c = sub * 8 + c0;        // 16B-chunk index 0..127 (8 f32 -> 8 fp16)
      const float* src = (c < 64) ? (pih + c * 8) : (phh + (c - 64) * 8);
      float4 va = *(const float4*)src;
      float4 vb = *(const float4*)(src + 4);
      __align__(16) unsigned short t8[8];
      t8[0] = f2h(va.x); t8[1] = f2h(va.y); t8[2] = f2h(va.z); t8[3] = f2h(va.w);
      t8[4] = f2h(vb.x); t8[5] = f2h(vb.y); t8[6] = f2h(vb.z); t8[7] = f2h(vb.w);
      *(int4*)&W_lds[row * 1024 + ((c ^ (row & 7)) * 8)] = *(const int4*)t8;
    }
  }

  // ---- per-thread bias constants (step-invariant) ----
  float bsum[4];
#pragma unroll
  for (int g = 0; g < 4; ++g) {
    int n = g * 512 + u0 + edu;
    bsum[g] = bih[n] + bhh[n];
  }
  __syncthreads();   // W_lds staged before first MFMA

  const char* wbase = (const char*)W_lds + wrow * 2048;
  const size_t xoff = (size_t)(mt * 16 + lr) * EE + kc * 8;  // per-lane x/h offset

  // ---- prime step (p=0): gates = x0 @ W_ih.T + b  (h = c = 0) ----
  float c_reg;
  {
    f32x4 acc = {0.f, 0.f, 0.f, 0.f};
    const unsigned short* xb = xseq + xoff;
#pragma unroll
    for (int kk = 0; kk < 16; ++kk) {
      uint4 xq = *(const uint4*)(xb + kk * 32);
      int4 wq = *(const int4*)(wbase + (((kk * 4 + kc) ^ (wrow & 7)) * 16));
      acc = __builtin_amdgcn_mfma_f32_16x16x32_f16(
          __builtin_bit_cast(f16x8, xq), __builtin_bit_cast(f16x8, wq), acc, 0, 0, 0);
    }
    {
      int g = nt * 2 + (lr >> 3);
      int du = lr & 7;
#pragma unroll
      for (int j = 0; j < 4; ++j) {
        int ss = mt * 16 + kc * 4 + j;
        gate_buf[g * 512 + du * 64 + (ss ^ (du << 3))] = acc[j];
      }
    }
    __syncthreads();
    {
      float gi = gate_buf[0 * 512 + edu * 64 + (es ^ (edu << 3))] + bsum[0];
      float gg = gate_buf[2 * 512 + edu * 64 + (es ^ (edu << 3))] + bsum[2];
      float go = gate_buf[3 * 512 + edu * 64 + (es ^ (edu << 3))] + bsum[3];
      float cn = sigm(gi) * tanh_fast(gg);
      float hn = sigm(go) * tanh_fast(cn);
      c_reg = cn;
      unsigned int hb = f2h(hn);
      unsigned int other = (unsigned int)__shfl_xor((int)hb, 1);
      if (!(l & 1))
        __hip_atomic_store(&hseq32[(size_t)es * 256 + bid * 4 + (edu >> 1)],
                           hb | (other << 16), __ATOMIC_RELAXED, __HIP_MEMORY_SCOPE_AGENT);
    }
  }

  // arrive(1)
  asm volatile("s_waitcnt vmcnt(0)" ::: "memory");
  __syncthreads();
  if (tid == 0)
    __hip_atomic_store(&flags[bid], 1, __ATOMIC_RELAXED, __HIP_MEMORY_SCOPE_AGENT);

  // x-half for step 1 (overlaps peers' arrivals)
  f32x4 acca = {0.f, 0.f, 0.f, 0.f};
  {
    const unsigned short* xb = xseq + (size_t)1 * (BB * HH) + xoff;
#pragma unroll
    for (int kk = 0; kk < 16; ++kk) {
      uint4 xq = *(const uint4*)(xb + kk * 32);
      int4 wq = *(const int4*)(wbase + (((kk * 4 + kc) ^ (wrow & 7)) * 16));
      acca = __builtin_amdgcn_mfma_f32_16x16x32_f16(
          __builtin_bit_cast(f16x8, xq), __builtin_bit_cast(f16x8, wq), acca, 0, 0, 0);
    }
  }

  // wait(1)
  if (tid < 64) {
    while (__hip_atomic_load(&flags[tid], __ATOMIC_RELAXED, __HIP_MEMORY_SCOPE_AGENT) < 1)
      __builtin_amdgcn_s_sleep(4);
  }
  __syncthreads();

  // ---- 32 recurrent steps ----
  for (int s = 1; s <= TT; ++s) {
    // h-half MFMAs from hseq[s-1] (the only barrier-dependent work)
    const unsigned short* hb2 = hseq16 + (size_t)(s - 1) * (BB * HH) + xoff;
    f32x4 acc = acca;
#pragma unroll
    for (int kk = 0; kk < 16; ++kk) {
      uint4 hq = *(const uint4*)(hb2 + kk * 32);
      int4 wq = *(const int4*)(wbase + ((((kk + 16) * 4 + kc) ^ (wrow & 7)) * 16));
      acc = __builtin_amdgcn_mfma_f32_16x16x32_f16(
          __builtin_bit_cast(f16x8, hq), __builtin_bit_cast(f16x8, wq), acc, 0, 0, 0);
    }

    // gate partials -> LDS (XOR-swizzled on sample index)
    {
      int g = nt * 2 + (lr >> 3);
      int du = lr & 7;
#pragma unroll
      for (int j = 0; j < 4; ++j) {
        int ss = mt * 16 + kc * 4 + j;
        gate_buf[g * 512 + du * 64 + (ss ^ (du << 3))] = acc[j];
      }
    }
    __syncthreads();

    // epilogue: one (es, edu) update per thread
    {
      float gi = gate_buf[0 * 512 + edu * 64 + (es ^ (edu << 3))] + bsum[0];
      float gf = gate_buf[1 * 512 + edu * 64 + (es ^ (edu << 3))] + bsum[1];
      float gg = gate_buf[2 * 512 + edu * 64 + (es ^ (edu << 3))] + bsum[2];
      float go = gate_buf[3 * 512 + edu * 64 + (es ^ (edu << 3))] + bsum[3];
      float cn = sigm(gf) * c_reg + sigm(gi) * tanh_fast(gg);
      float hn = sigm(go) * tanh_fast(cn);
      c_reg = cn;
      unsigned int hb = f2h(hn);
      unsigned int other = (unsigned int)__shfl_xor((int)hb, 1);
      if (!(l & 1))
        __hip_atomic_store(&hseq32[(size_t)s * 16384 + es * 256 + bid * 4 + (edu >> 1)],
                           hb | (other << 16), __ATOMIC_RELAXED, __HIP_MEMORY_SCOPE_AGENT);
    }

    if (s < TT) {
      // arrive(s+1)
      asm volatile("s_waitcnt vmcnt(0)" ::: "memory");
      __syncthreads();
      if (tid == 0)
        __hip_atomic_store(&flags[bid], s + 1, __ATOMIC_RELAXED, __HIP_MEMORY_SCOPE_AGENT);

      // x-half for step s+1 (hidden under peers' arrival + poll window)
      acca = (f32x4){0.f, 0.f, 0.f, 0.f};
      const unsigned short* xb = xseq + (size_t)(s + 1) * (BB * HH) + xoff;
#pragma unroll
      for (int kk = 0; kk < 16; ++kk) {
        uint4 xq = *(const uint4*)(xb + kk * 32);
        int4 wq = *(const int4*)(wbase + (((kk * 4 + kc) ^ (wrow & 7)) * 16));
        acca = __builtin_amdgcn_mfma_f32_16x16x32_f16(
            __builtin_bit_cast(f16x8, xq), __builtin_bit_cast(f16x8, wq), acca, 0, 0, 0);
      }

      // wait(s+1)
      if (tid < 64) {
        while (__hip_atomic_load(&flags[tid], __ATOMIC_RELAXED, __HIP_MEMORY_SCOPE_AGENT) < s + 1)
          __builtin_amdgcn_s_sleep(4);
      }
      __syncthreads();
    }
  }
  // dispatch-end writeback publishes hseq to k_gemm_out (r12-r17 precedent)
}

// ---------------------------------------------------------------------------
// Kernel 3: Out = hseq[1..32] @ W_out.T + b_out   [fp16 MFMA, f32 out]
// (verbatim r16/r17 — double-buffered h staging, W slice in registers.)
// ---------------------------------------------------------------------------
__global__ __launch_bounds__(512) void k_gemm_out(const unsigned short* __restrict__ hseq,
                                                  const float* __restrict__ Wout,
                                                  const float* __restrict__ bout,
                                                  float* __restrict__ out) {
  __shared__ __align__(16) unsigned short As[2][BB * HH];   // 2 x 64 KB
  const int tid = threadIdx.x;
  const int l = tid & 63;
  const int w = tid >> 6;
  const int n00 = blockIdx.x * 128;
  const int bcol = w * 16 + (l >> 4) * 4;
  const float4 bo0 = *(const float4*)(bout + n00 + bcol);

  // preload W_out slice f32 -> f16 fragments in registers (once)
  const int vr0 = n00 + w * 16 + (l & 15);
  const int kb = (l >> 4) * 8;
  uint4 w0r[16];
#pragma unroll
  for (int kt = 0; kt < 16; ++kt) {
    const float* p = Wout + (size_t)vr0 * HH + kt * 32 + kb;
    float4 a = *(const float4*)p;
    float4 b = *(const float4*)(p + 4);
    __align__(16) unsigned short t8[8];
    t8[0] = f2h(a.x); t8[1] = f2h(a.y); t8[2] = f2h(a.z); t8[3] = f2h(a.w);
    t8[4] = f2h(b.x); t8[5] = f2h(b.y); t8[6] = f2h(b.z); t8[7] = f2h(b.w);
    w0r[kt] = *(const uint4*)t8;
  }

  // stage step 1 into As[0]
  const unsigned short* hs1 = hseq + (size_t)1 * (BB * HH);
#pragma unroll
  for (int it = 0; it < 8; ++it) {
    int ci = it * 512 + tid;
    int row = ci >> 6, cd = ci & 63;
    gload_lds16(hs1 + (size_t)row * HH + (cd ^ (row & 7)) * 8, As[0] + ci * 8);
  }

  int cur = 0;
  for (int s = 1; s <= TT; ++s) {
    asm volatile("s_waitcnt vmcnt(0)" ::: "memory");   // stage of As[cur] done
    __syncthreads();                                   // + prev reads of As[cur] done

    if (s < TT) {
      const unsigned short* hs = hseq + (size_t)(s + 1) * (BB * HH);
#pragma unroll
      for (int it = 0; it < 8; ++it) {
        int ci = it * 512 + tid;
        int row = ci >> 6, cd = ci & 63;
        gload_lds16(hs + (size_t)row * HH + (cd ^ (row & 7)) * 8, As[cur ^ 1] + ci * 8);
      }
    }

    const unsigned short* Ab = As[cur];
    f32x4 acc0[4];
#pragma unroll
    for (int m = 0; m < 4; ++m) acc0[m] = (f32x4){0.f, 0.f, 0.f, 0.f};
#pragma unroll
    for (int m = 0; m < 4; ++m) {
      int row = m * 16 + (l & 15);
#pragma unroll
      for (int kt = 0; kt < 16; ++kt) {
        int c = kt * 4 + (l >> 4);
        f16x8 af = *(const f16x8*)&Ab[row * HH + (c ^ (row & 7)) * 8];
        // mfma(W, h): W-rows -> row-field (out col); h-rows -> col (out row)
        acc0[m] = __builtin_amdgcn_mfma_f32_16x16x32_f16(
            __builtin_bit_cast(f16x8, w0r[kt]), af, acc0[m], 0, 0, 0);
      }
    }
#pragma unroll
    for (int m = 0; m < 4; ++m) {
      int b = m * 16 + (l & 15);
      float* orow = out + ((size_t)(b * TT + (s - 1))) * VV + n00 + bcol;
      float4 v;
      v.x = acc0[m][0] + bo0.x;
      v.y = acc0[m][1] + bo0.y;
      v.z = acc0[m][2] + bo0.z;
      v.w = acc0[m][3] + bo0.w;
      *(float4*)orow = v;
    }
    cur ^= 1;
  }
}

// ---------------------------------------------------------------------------
extern "C" void kernel_launch(void* const* d_in, const int* in_sizes, int n_in,
                              void* d_out, int out_size, void* d_ws, size_t ws_size,
                              hipStream_t stream) {
  const float* feat = (const float*)d_in[0];
  const int* cap = (const int*)d_in[1];
  // d_in[2] = seq_len (constant 32)
  const float* emb = (const float*)d_in[3];
  const float* Wih = (const float*)d_in[4];
  const float* Whh = (const float*)d_in[5];
  const float* bih = (const float*)d_in[6];
  const float* bhh = (const float*)d_in[7];
  const float* Wout = (const float*)d_in[8];
  const float* bout = (const float*)d_in[9];
  float* out = (float*)d_out;

  char* ws = (char*)d_ws;
  unsigned short* xseq = (unsigned short*)ws;                 //  2,162,688 (33 x 64 x 512 fp16)
  char* hseq = ws + 2162688;                                  //  2,162,688
  int* flags = (int*)(ws + 4325376);                          //      4,096

  hipMemsetAsync(flags, 0, 4096, stream);
  k_embed<<<dim3(2112), dim3(128), 0, stream>>>(feat, cap, emb, xseq);
  k_rnn<<<dim3(64), dim3(512), 0, stream>>>(xseq, Wih, Whh, bih, bhh, hseq, flags);
  k_gemm_out<<<dim3(250), dim3(512), 0, stream>>>((const unsigned short*)hseq, Wout, bout, out);
}

// Round 19
// 395.104 us; speedup vs baseline: 1.2344x; 1.0588x over previous
//
#include <hip/hip_runtime.h>
#include <stdint.h>

// Problem dims (fixed)
#define BB 64
#define TT 32
#define EE 512
#define HH 512
#define VV 32000
#define G4 2048

typedef _Float16 f16x8 __attribute__((ext_vector_type(8)));
typedef float f32x4 __attribute__((ext_vector_type(4)));

__device__ __forceinline__ unsigned short f2h(float f) {
  return __builtin_bit_cast(unsigned short, (_Float16)f);   // RNE hw cvt
}
__device__ __forceinline__ void gload_lds16(const unsigned short* g, unsigned short* l) {
  __builtin_amdgcn_global_load_lds((const __attribute__((address_space(1))) void*)g,
                                   (__attribute__((address_space(3))) void*)l, 16, 0, 0);
}
__device__ __forceinline__ float sigm(float x) { return 1.f / (1.f + __expf(-x)); }
__device__ __forceinline__ float tanh_fast(float x) {
  return 1.f - 2.f / (__expf(2.f * x) + 1.f);   // stable at +-inf
}

// ---------------------------------------------------------------------------
// Kernel 1: gather+cast x inputs -> fp16 xseq[33][64][512].  (verbatim r17/18)
// ---------------------------------------------------------------------------
__global__ __launch_bounds__(128) void k_embed(const float* __restrict__ feat,
                                               const int* __restrict__ cap,
                                               const float* __restrict__ emb,
                                               unsigned short* __restrict__ xseq) {
  const int r = blockIdx.x;  // 0..2111
  const int t = threadIdx.x; // 128 thr x 4 f32
  const float* src;
  if (r < BB) {
    src = feat + (size_t)r * EE;
  } else {
    int p = r >> 6, b = r & 63;
    src = emb + (size_t)cap[b * TT + (p - 1)] * EE;
  }
  float4 v = ((const float4*)src)[t];
  ushort4 o;
  o.x = f2h(v.x); o.y = f2h(v.y); o.z = f2h(v.z); o.w = f2h(v.w);
  ((ushort4*)(xseq + (size_t)r * EE))[t] = o;
}

// ---------------------------------------------------------------------------
// Kernel 2: persistent LSTM recurrence, K=1024 fused-input form, x-half
// hoisted into the barrier window.  (verbatim r18 — passed, 286us)
// ---------------------------------------------------------------------------
__global__ __launch_bounds__(512) void k_rnn(const unsigned short* __restrict__ xseq,
                                             const float* __restrict__ Wih,
                                             const float* __restrict__ Whh,
                                             const float* __restrict__ bih,
                                             const float* __restrict__ bhh,
                                             char* hseq_base,
                                             int* __restrict__ flags) {
  __shared__ __align__(16) unsigned short W_lds[32 * 1024];  // fp16, 64 KB
  __shared__ float gate_buf[2048];                           // 8 KB
  unsigned short* hseq16 = (unsigned short*)hseq_base;
  unsigned int* hseq32 = (unsigned int*)hseq_base;

  const int tid = threadIdx.x;
  const int bid = blockIdx.x;
  const int u0 = bid * 8;
  const int l = tid & 63;
  const int w = tid >> 6;          // wave 0..7
  const int lr = l & 15;
  const int kc = l >> 4;           // 0..3
  const int nt = w & 1;            // n-tile (W'-row half: 0 = gates i,f; 1 = g,o)
  const int mt = w >> 1;           // m-tile (16-sample group)
  const int es = w * 8 + (l >> 3); // 0..63
  const int edu = l & 7;           // 0..7
  const int wrow = nt * 16 + lr;   // LDS W'-row this lane reads

  // ---- stage [W_ih | W_hh] (f32 -> fp16) into LDS, chunk-XOR swizzled ----
  {
    int row = tid >> 4;            // 0..31 (= g*8 + du)
    int sub = tid & 15;
    int g = row >> 3, du = row & 7;
    const float* pih = Wih + (size_t)(g * 512 + u0 + du) * EE;
    const float* phh = Whh + (size_t)(g * 512 + u0 + du) * HH;
#pragma unroll
    for (int c0 = 0; c0 < 8; ++c0) {
      int c = sub * 8 + c0;        // 16B-chunk index 0..127
      const float* src = (c < 64) ? (pih + c * 8) : (phh + (c - 64) * 8);
      float4 va = *(const float4*)src;
      float4 vb = *(const float4*)(src + 4);
      __align__(16) unsigned short t8[8];
      t8[0] = f2h(va.x); t8[1] = f2h(va.y); t8[2] = f2h(va.z); t8[3] = f2h(va.w);
      t8[4] = f2h(vb.x); t8[5] = f2h(vb.y); t8[6] = f2h(vb.z); t8[7] = f2h(vb.w);
      *(int4*)&W_lds[row * 1024 + ((c ^ (row & 7)) * 8)] = *(const int4*)t8;
    }
  }

  // ---- per-thread bias constants (step-invariant) ----
  float bsum[4];
#pragma unroll
  for (int g = 0; g < 4; ++g) {
    int n = g * 512 + u0 + edu;
    bsum[g] = bih[n] + bhh[n];
  }
  __syncthreads();   // W_lds staged before first MFMA

  const char* wbase = (const char*)W_lds + wrow * 2048;
  const size_t xoff = (size_t)(mt * 16 + lr) * EE + kc * 8;  // per-lane x/h offset

  // ---- prime step (p=0): gates = x0 @ W_ih.T + b  (h = c = 0) ----
  float c_reg;
  {
    f32x4 acc = {0.f, 0.f, 0.f, 0.f};
    const unsigned short* xb = xseq + xoff;
#pragma unroll
    for (int kk = 0; kk < 16; ++kk) {
      uint4 xq = *(const uint4*)(xb + kk * 32);
      int4 wq = *(const int4*)(wbase + (((kk * 4 + kc) ^ (wrow & 7)) * 16));
      acc = __builtin_amdgcn_mfma_f32_16x16x32_f16(
          __builtin_bit_cast(f16x8, xq), __builtin_bit_cast(f16x8, wq), acc, 0, 0, 0);
    }
    {
      int g = nt * 2 + (lr >> 3);
      int du = lr & 7;
#pragma unroll
      for (int j = 0; j < 4; ++j) {
        int ss = mt * 16 + kc * 4 + j;
        gate_buf[g * 512 + du * 64 + (ss ^ (du << 3))] = acc[j];
      }
    }
    __syncthreads();
    {
      float gi = gate_buf[0 * 512 + edu * 64 + (es ^ (edu << 3))] + bsum[0];
      float gg = gate_buf[2 * 512 + edu * 64 + (es ^ (edu << 3))] + bsum[2];
      float go = gate_buf[3 * 512 + edu * 64 + (es ^ (edu << 3))] + bsum[3];
      float cn = sigm(gi) * tanh_fast(gg);
      float hn = sigm(go) * tanh_fast(cn);
      c_reg = cn;
      unsigned int hb = f2h(hn);
      unsigned int other = (unsigned int)__shfl_xor((int)hb, 1);
      if (!(l & 1))
        __hip_atomic_store(&hseq32[(size_t)es * 256 + bid * 4 + (edu >> 1)],
                           hb | (other << 16), __ATOMIC_RELAXED, __HIP_MEMORY_SCOPE_AGENT);
    }
  }

  // arrive(1)
  asm volatile("s_waitcnt vmcnt(0)" ::: "memory");
  __syncthreads();
  if (tid == 0)
    __hip_atomic_store(&flags[bid], 1, __ATOMIC_RELAXED, __HIP_MEMORY_SCOPE_AGENT);

  // x-half for step 1 (overlaps peers' arrivals)
  f32x4 acca = {0.f, 0.f, 0.f, 0.f};
  {
    const unsigned short* xb = xseq + (size_t)1 * (BB * HH) + xoff;
#pragma unroll
    for (int kk = 0; kk < 16; ++kk) {
      uint4 xq = *(const uint4*)(xb + kk * 32);
      int4 wq = *(const int4*)(wbase + (((kk * 4 + kc) ^ (wrow & 7)) * 16));
      acca = __builtin_amdgcn_mfma_f32_16x16x32_f16(
          __builtin_bit_cast(f16x8, xq), __builtin_bit_cast(f16x8, wq), acca, 0, 0, 0);
    }
  }

  // wait(1)
  if (tid < 64) {
    while (__hip_atomic_load(&flags[tid], __ATOMIC_RELAXED, __HIP_MEMORY_SCOPE_AGENT) < 1)
      __builtin_amdgcn_s_sleep(4);
  }
  __syncthreads();

  // ---- 32 recurrent steps ----
  for (int s = 1; s <= TT; ++s) {
    const unsigned short* hb2 = hseq16 + (size_t)(s - 1) * (BB * HH) + xoff;
    f32x4 acc = acca;
#pragma unroll
    for (int kk = 0; kk < 16; ++kk) {
      uint4 hq = *(const uint4*)(hb2 + kk * 32);
      int4 wq = *(const int4*)(wbase + ((((kk + 16) * 4 + kc) ^ (wrow & 7)) * 16));
      acc = __builtin_amdgcn_mfma_f32_16x16x32_f16(
          __builtin_bit_cast(f16x8, hq), __builtin_bit_cast(f16x8, wq), acc, 0, 0, 0);
    }

    // gate partials -> LDS (XOR-swizzled on sample index)
    {
      int g = nt * 2 + (lr >> 3);
      int du = lr & 7;
#pragma unroll
      for (int j = 0; j < 4; ++j) {
        int ss = mt * 16 + kc * 4 + j;
        gate_buf[g * 512 + du * 64 + (ss ^ (du << 3))] = acc[j];
      }
    }
    __syncthreads();

    // epilogue: one (es, edu) update per thread
    {
      float gi = gate_buf[0 * 512 + edu * 64 + (es ^ (edu << 3))] + bsum[0];
      float gf = gate_buf[1 * 512 + edu * 64 + (es ^ (edu << 3))] + bsum[1];
      float gg = gate_buf[2 * 512 + edu * 64 + (es ^ (edu << 3))] + bsum[2];
      float go = gate_buf[3 * 512 + edu * 64 + (es ^ (edu << 3))] + bsum[3];
      float cn = sigm(gf) * c_reg + sigm(gi) * tanh_fast(gg);
      float hn = sigm(go) * tanh_fast(cn);
      c_reg = cn;
      unsigned int hb = f2h(hn);
      unsigned int other = (unsigned int)__shfl_xor((int)hb, 1);
      if (!(l & 1))
        __hip_atomic_store(&hseq32[(size_t)s * 16384 + es * 256 + bid * 4 + (edu >> 1)],
                           hb | (other << 16), __ATOMIC_RELAXED, __HIP_MEMORY_SCOPE_AGENT);
    }

    if (s < TT) {
      // arrive(s+1)
      asm volatile("s_waitcnt vmcnt(0)" ::: "memory");
      __syncthreads();
      if (tid == 0)
        __hip_atomic_store(&flags[bid], s + 1, __ATOMIC_RELAXED, __HIP_MEMORY_SCOPE_AGENT);

      // x-half for step s+1 (hidden under peers' arrival + poll window)
      acca = (f32x4){0.f, 0.f, 0.f, 0.f};
      const unsigned short* xb = xseq + (size_t)(s + 1) * (BB * HH) + xoff;
#pragma unroll
      for (int kk = 0; kk < 16; ++kk) {
        uint4 xq = *(const uint4*)(xb + kk * 32);
        int4 wq = *(const int4*)(wbase + (((kk * 4 + kc) ^ (wrow & 7)) * 16));
        acca = __builtin_amdgcn_mfma_f32_16x16x32_f16(
            __builtin_bit_cast(f16x8, xq), __builtin_bit_cast(f16x8, wq), acca, 0, 0, 0);
      }

      // wait(s+1)
      if (tid < 64) {
        while (__hip_atomic_load(&flags[tid], __ATOMIC_RELAXED, __HIP_MEMORY_SCOPE_AGENT) < s + 1)
          __builtin_amdgcn_s_sleep(4);
      }
      __syncthreads();
    }
  }
  // dispatch-end writeback publishes hseq to k_gemm_out (r12-r18 precedent)
}

// ---------------------------------------------------------------------------
// Kernel 3: Out = hseq[1..32] @ W_out.T + b_out   [fp16 MFMA, f32 out]
// v3: wave re-tiling 2 row-groups x 4 col-groups.  Each wave owns 32 rows x
// 32 cols: W = TWO col-tiles in registers (128 VGPR), af ds_read count
// halves (32/wave/step, tile read 4x not 8x) and each af read feeds 2 MFMAs
// — removes the 1:1 ds_read:MFMA LDS-throughput bound (was ~2.6us/step).
// Double-buffered h staging (verbatim r16-18).
// ---------------------------------------------------------------------------
__global__ __launch_bounds__(512) void k_gemm_out(const unsigned short* __restrict__ hseq,
                                                  const float* __restrict__ Wout,
                                                  const float* __restrict__ bout,
                                                  float* __restrict__ out) {
  __shared__ __align__(16) unsigned short As[2][BB * HH];   // 2 x 64 KB
  const int tid = threadIdx.x;
  const int l = tid & 63;
  const int w = tid >> 6;
  const int wr = w >> 2;           // row-group 0/1 (32 rows)
  const int wc = w & 3;            // col-group 0..3 (32 cols)
  const int n00 = blockIdx.x * 128;
  const int bcol4 = (l >> 4) * 4;  // 4-float sub-col within a 16-col tile

  // preload TWO W_out col-tiles f32 -> f16 fragments in registers (once)
  const int kb = (l >> 4) * 8;
  uint4 w0r[2][16];
  float4 bo[2];
#pragma unroll
  for (int ct = 0; ct < 2; ++ct) {
    const int vr = n00 + wc * 32 + ct * 16 + (l & 15);
    bo[ct] = *(const float4*)(bout + n00 + wc * 32 + ct * 16 + bcol4);
#pragma unroll
    for (int kt = 0; kt < 16; ++kt) {
      const float* p = Wout + (size_t)vr * HH + kt * 32 + kb;
      float4 a = *(const float4*)p;
      float4 b = *(const float4*)(p + 4);
      __align__(16) unsigned short t8[8];
      t8[0] = f2h(a.x); t8[1] = f2h(a.y); t8[2] = f2h(a.z); t8[3] = f2h(a.w);
      t8[4] = f2h(b.x); t8[5] = f2h(b.y); t8[6] = f2h(b.z); t8[7] = f2h(b.w);
      w0r[ct][kt] = *(const uint4*)t8;
    }
  }

  // stage step 1 into As[0]
  const unsigned short* hs1 = hseq + (size_t)1 * (BB * HH);
#pragma unroll
  for (int it = 0; it < 8; ++it) {
    int ci = it * 512 + tid;
    int row = ci >> 6, cd = ci & 63;
    gload_lds16(hs1 + (size_t)row * HH + (cd ^ (row & 7)) * 8, As[0] + ci * 8);
  }

  int cur = 0;
  for (int s = 1; s <= TT; ++s) {
    asm volatile("s_waitcnt vmcnt(0)" ::: "memory");   // stage of As[cur] done
    __syncthreads();                                   // + prev reads of As[cur] done

    if (s < TT) {
      const unsigned short* hs = hseq + (size_t)(s + 1) * (BB * HH);
#pragma unroll
      for (int it = 0; it < 8; ++it) {
        int ci = it * 512 + tid;
        int row = ci >> 6, cd = ci & 63;
        gload_lds16(hs + (size_t)row * HH + (cd ^ (row & 7)) * 8, As[cur ^ 1] + ci * 8);
      }
    }

    const unsigned short* Ab = As[cur];
    f32x4 acc[2][2];   // [mg][ct]
#pragma unroll
    for (int mg = 0; mg < 2; ++mg)
#pragma unroll
      for (int ct = 0; ct < 2; ++ct) acc[mg][ct] = (f32x4){0.f, 0.f, 0.f, 0.f};

#pragma unroll
    for (int mg = 0; mg < 2; ++mg) {
      int row = wr * 32 + mg * 16 + (l & 15);
#pragma unroll
      for (int kt = 0; kt < 16; ++kt) {
        int c = kt * 4 + (l >> 4);
        f16x8 af = *(const f16x8*)&Ab[row * HH + (c ^ (row & 7)) * 8];
        // one af read feeds TWO MFMAs (col-tiles 0 and 1)
        acc[mg][0] = __builtin_amdgcn_mfma_f32_16x16x32_f16(
            __builtin_bit_cast(f16x8, w0r[0][kt]), af, acc[mg][0], 0, 0, 0);
        acc[mg][1] = __builtin_amdgcn_mfma_f32_16x16x32_f16(
            __builtin_bit_cast(f16x8, w0r[1][kt]), af, acc[mg][1], 0, 0, 0);
      }
    }

#pragma unroll
    for (int mg = 0; mg < 2; ++mg) {
      int b = wr * 32 + mg * 16 + (l & 15);
      float* orow = out + ((size_t)(b * TT + (s - 1))) * VV + n00 + wc * 32 + bcol4;
#pragma unroll
      for (int ct = 0; ct < 2; ++ct) {
        float4 v;
        v.x = acc[mg][ct][0] + bo[ct].x;
        v.y = acc[mg][ct][1] + bo[ct].y;
        v.z = acc[mg][ct][2] + bo[ct].z;
        v.w = acc[mg][ct][3] + bo[ct].w;
        *(float4*)(orow + ct * 16) = v;
      }
    }
    cur ^= 1;
  }
}

// ---------------------------------------------------------------------------
extern "C" void kernel_launch(void* const* d_in, const int* in_sizes, int n_in,
                              void* d_out, int out_size, void* d_ws, size_t ws_size,
                              hipStream_t stream) {
  const float* feat = (const float*)d_in[0];
  const int* cap = (const int*)d_in[1];
  // d_in[2] = seq_len (constant 32)
  const float* emb = (const float*)d_in[3];
  const float* Wih = (const float*)d_in[4];
  const float* Whh = (const float*)d_in[5];
  const float* bih = (const float*)d_in[6];
  const float* bhh = (const float*)d_in[7];
  const float* Wout = (const float*)d_in[8];
  const float* bout = (const float*)d_in[9];
  float* out = (float*)d_out;

  char* ws = (char*)d_ws;
  unsigned short* xseq = (unsigned short*)ws;                 //  2,162,688 (33 x 64 x 512 fp16)
  char* hseq = ws + 2162688;                                  //  2,162,688
  int* flags = (int*)(ws + 4325376);                          //      4,096

  hipMemsetAsync(flags, 0, 4096, stream);
  k_embed<<<dim3(2112), dim3(128), 0, stream>>>(feat, cap, emb, xseq);
  k_rnn<<<dim3(64), dim3(512), 0, stream>>>(xseq, Wih, Whh, bih, bhh, hseq, flags);
  k_gemm_out<<<dim3(250), dim3(512), 0, stream>>>((const unsigned short*)hseq, Wout, bout, out);
}

// Round 20
// 394.103 us; speedup vs baseline: 1.2375x; 1.0025x over previous
//
#include <hip/hip_runtime.h>
#include <stdint.h>

// Problem dims (fixed)
#define BB 64
#define TT 32
#define EE 512
#define HH 512
#define VV 32000
#define G4 2048

typedef _Float16 f16x8 __attribute__((ext_vector_type(8)));
typedef float f32x4 __attribute__((ext_vector_type(4)));

__device__ __forceinline__ unsigned short f2h(float f) {
  return __builtin_bit_cast(unsigned short, (_Float16)f);   // RNE hw cvt
}
__device__ __forceinline__ void gload_lds16(const unsigned short* g, unsigned short* l) {
  __builtin_amdgcn_global_load_lds((const __attribute__((address_space(1))) void*)g,
                                   (__attribute__((address_space(3))) void*)l, 16, 0, 0);
}
__device__ __forceinline__ float sigm(float x) { return 1.f / (1.f + __expf(-x)); }
__device__ __forceinline__ float tanh_fast(float x) {
  return 1.f - 2.f / (__expf(2.f * x) + 1.f);   // stable at +-inf
}

// ---------------------------------------------------------------------------
// Kernel 1: gather+cast x inputs -> fp16 xseq[33][64][512].  (verbatim r17-19)
// ---------------------------------------------------------------------------
__global__ __launch_bounds__(128) void k_embed(const float* __restrict__ feat,
                                               const int* __restrict__ cap,
                                               const float* __restrict__ emb,
                                               unsigned short* __restrict__ xseq) {
  const int r = blockIdx.x;  // 0..2111
  const int t = threadIdx.x; // 128 thr x 4 f32
  const float* src;
  if (r < BB) {
    src = feat + (size_t)r * EE;
  } else {
    int p = r >> 6, b = r & 63;
    src = emb + (size_t)cap[b * TT + (p - 1)] * EE;
  }
  float4 v = ((const float4*)src)[t];
  ushort4 o;
  o.x = f2h(v.x); o.y = f2h(v.y); o.z = f2h(v.z); o.w = f2h(v.w);
  ((ushort4*)(xseq + (size_t)r * EE))[t] = o;
}

// ---------------------------------------------------------------------------
// Kernel 2: persistent LSTM recurrence, K=1024 fused-input form, x-half
// hoisted into the barrier window.  (verbatim r18/r19 — passed, 286us)
// ---------------------------------------------------------------------------
__global__ __launch_bounds__(512) void k_rnn(const unsigned short* __restrict__ xseq,
                                             const float* __restrict__ Wih,
                                             const float* __restrict__ Whh,
                                             const float* __restrict__ bih,
                                             const float* __restrict__ bhh,
                                             char* hseq_base,
                                             int* __restrict__ flags) {
  __shared__ __align__(16) unsigned short W_lds[32 * 1024];  // fp16, 64 KB
  __shared__ float gate_buf[2048];                           // 8 KB
  unsigned short* hseq16 = (unsigned short*)hseq_base;
  unsigned int* hseq32 = (unsigned int*)hseq_base;

  const int tid = threadIdx.x;
  const int bid = blockIdx.x;
  const int u0 = bid * 8;
  const int l = tid & 63;
  const int w = tid >> 6;          // wave 0..7
  const int lr = l & 15;
  const int kc = l >> 4;           // 0..3
  const int nt = w & 1;            // n-tile (W'-row half: 0 = gates i,f; 1 = g,o)
  const int mt = w >> 1;           // m-tile (16-sample group)
  const int es = w * 8 + (l >> 3); // 0..63
  const int edu = l & 7;           // 0..7
  const int wrow = nt * 16 + lr;   // LDS W'-row this lane reads

  // ---- stage [W_ih | W_hh] (f32 -> fp16) into LDS, chunk-XOR swizzled ----
  {
    int row = tid >> 4;            // 0..31 (= g*8 + du)
    int sub = tid & 15;
    int g = row >> 3, du = row & 7;
    const float* pih = Wih + (size_t)(g * 512 + u0 + du) * EE;
    const float* phh = Whh + (size_t)(g * 512 + u0 + du) * HH;
#pragma unroll
    for (int c0 = 0; c0 < 8; ++c0) {
      int c = sub * 8 + c0;        // 16B-chunk index 0..127
      const float* src = (c < 64) ? (pih + c * 8) : (phh + (c - 64) * 8);
      float4 va = *(const float4*)src;
      float4 vb = *(const float4*)(src + 4);
      __align__(16) unsigned short t8[8];
      t8[0] = f2h(va.x); t8[1] = f2h(va.y); t8[2] = f2h(va.z); t8[3] = f2h(va.w);
      t8[4] = f2h(vb.x); t8[5] = f2h(vb.y); t8[6] = f2h(vb.z); t8[7] = f2h(vb.w);
      *(int4*)&W_lds[row * 1024 + ((c ^ (row & 7)) * 8)] = *(const int4*)t8;
    }
  }

  // ---- per-thread bias constants (step-invariant) ----
  float bsum[4];
#pragma unroll
  for (int g = 0; g < 4; ++g) {
    int n = g * 512 + u0 + edu;
    bsum[g] = bih[n] + bhh[n];
  }
  __syncthreads();   // W_lds staged before first MFMA

  const char* wbase = (const char*)W_lds + wrow * 2048;
  const size_t xoff = (size_t)(mt * 16 + lr) * EE + kc * 8;  // per-lane x/h offset

  // ---- prime step (p=0): gates = x0 @ W_ih.T + b  (h = c = 0) ----
  float c_reg;
  {
    f32x4 acc = {0.f, 0.f, 0.f, 0.f};
    const unsigned short* xb = xseq + xoff;
#pragma unroll
    for (int kk = 0; kk < 16; ++kk) {
      uint4 xq = *(const uint4*)(xb + kk * 32);
      int4 wq = *(const int4*)(wbase + (((kk * 4 + kc) ^ (wrow & 7)) * 16));
      acc = __builtin_amdgcn_mfma_f32_16x16x32_f16(
          __builtin_bit_cast(f16x8, xq), __builtin_bit_cast(f16x8, wq), acc, 0, 0, 0);
    }
    {
      int g = nt * 2 + (lr >> 3);
      int du = lr & 7;
#pragma unroll
      for (int j = 0; j < 4; ++j) {
        int ss = mt * 16 + kc * 4 + j;
        gate_buf[g * 512 + du * 64 + (ss ^ (du << 3))] = acc[j];
      }
    }
    __syncthreads();
    {
      float gi = gate_buf[0 * 512 + edu * 64 + (es ^ (edu << 3))] + bsum[0];
      float gg = gate_buf[2 * 512 + edu * 64 + (es ^ (edu << 3))] + bsum[2];
      float go = gate_buf[3 * 512 + edu * 64 + (es ^ (edu << 3))] + bsum[3];
      float cn = sigm(gi) * tanh_fast(gg);
      float hn = sigm(go) * tanh_fast(cn);
      c_reg = cn;
      unsigned int hb = f2h(hn);
      unsigned int other = (unsigned int)__shfl_xor((int)hb, 1);
      if (!(l & 1))
        __hip_atomic_store(&hseq32[(size_t)es * 256 + bid * 4 + (edu >> 1)],
                           hb | (other << 16), __ATOMIC_RELAXED, __HIP_MEMORY_SCOPE_AGENT);
    }
  }

  // arrive(1)
  asm volatile("s_waitcnt vmcnt(0)" ::: "memory");
  __syncthreads();
  if (tid == 0)
    __hip_atomic_store(&flags[bid], 1, __ATOMIC_RELAXED, __HIP_MEMORY_SCOPE_AGENT);

  // x-half for step 1 (overlaps peers' arrivals)
  f32x4 acca = {0.f, 0.f, 0.f, 0.f};
  {
    const unsigned short* xb = xseq + (size_t)1 * (BB * HH) + xoff;
#pragma unroll
    for (int kk = 0; kk < 16; ++kk) {
      uint4 xq = *(const uint4*)(xb + kk * 32);
      int4 wq = *(const int4*)(wbase + (((kk * 4 + kc) ^ (wrow & 7)) * 16));
      acca = __builtin_amdgcn_mfma_f32_16x16x32_f16(
          __builtin_bit_cast(f16x8, xq), __builtin_bit_cast(f16x8, wq), acca, 0, 0, 0);
    }
  }

  // wait(1)
  if (tid < 64) {
    while (__hip_atomic_load(&flags[tid], __ATOMIC_RELAXED, __HIP_MEMORY_SCOPE_AGENT) < 1)
      __builtin_amdgcn_s_sleep(4);
  }
  __syncthreads();

  // ---- 32 recurrent steps ----
  for (int s = 1; s <= TT; ++s) {
    const unsigned short* hb2 = hseq16 + (size_t)(s - 1) * (BB * HH) + xoff;
    f32x4 acc = acca;
#pragma unroll
    for (int kk = 0; kk < 16; ++kk) {
      uint4 hq = *(const uint4*)(hb2 + kk * 32);
      int4 wq = *(const int4*)(wbase + ((((kk + 16) * 4 + kc) ^ (wrow & 7)) * 16));
      acc = __builtin_amdgcn_mfma_f32_16x16x32_f16(
          __builtin_bit_cast(f16x8, hq), __builtin_bit_cast(f16x8, wq), acc, 0, 0, 0);
    }

    // gate partials -> LDS (XOR-swizzled on sample index)
    {
      int g = nt * 2 + (lr >> 3);
      int du = lr & 7;
#pragma unroll
      for (int j = 0; j < 4; ++j) {
        int ss = mt * 16 + kc * 4 + j;
        gate_buf[g * 512 + du * 64 + (ss ^ (du << 3))] = acc[j];
      }
    }
    __syncthreads();

    // epilogue: one (es, edu) update per thread
    {
      float gi = gate_buf[0 * 512 + edu * 64 + (es ^ (edu << 3))] + bsum[0];
      float gf = gate_buf[1 * 512 + edu * 64 + (es ^ (edu << 3))] + bsum[1];
      float gg = gate_buf[2 * 512 + edu * 64 + (es ^ (edu << 3))] + bsum[2];
      float go = gate_buf[3 * 512 + edu * 64 + (es ^ (edu << 3))] + bsum[3];
      float cn = sigm(gf) * c_reg + sigm(gi) * tanh_fast(gg);
      float hn = sigm(go) * tanh_fast(cn);
      c_reg = cn;
      unsigned int hb = f2h(hn);
      unsigned int other = (unsigned int)__shfl_xor((int)hb, 1);
      if (!(l & 1))
        __hip_atomic_store(&hseq32[(size_t)s * 16384 + es * 256 + bid * 4 + (edu >> 1)],
                           hb | (other << 16), __ATOMIC_RELAXED, __HIP_MEMORY_SCOPE_AGENT);
    }

    if (s < TT) {
      // arrive(s+1)
      asm volatile("s_waitcnt vmcnt(0)" ::: "memory");
      __syncthreads();
      if (tid == 0)
        __hip_atomic_store(&flags[bid], s + 1, __ATOMIC_RELAXED, __HIP_MEMORY_SCOPE_AGENT);

      // x-half for step s+1 (hidden under peers' arrival + poll window)
      acca = (f32x4){0.f, 0.f, 0.f, 0.f};
      const unsigned short* xb = xseq + (size_t)(s + 1) * (BB * HH) + xoff;
#pragma unroll
      for (int kk = 0; kk < 16; ++kk) {
        uint4 xq = *(const uint4*)(xb + kk * 32);
        int4 wq = *(const int4*)(wbase + (((kk * 4 + kc) ^ (wrow & 7)) * 16));
        acca = __builtin_amdgcn_mfma_f32_16x16x32_f16(
            __builtin_bit_cast(f16x8, xq), __builtin_bit_cast(f16x8, wq), acca, 0, 0, 0);
      }

      // wait(s+1)
      if (tid < 64) {
        while (__hip_atomic_load(&flags[tid], __ATOMIC_RELAXED, __HIP_MEMORY_SCOPE_AGENT) < s + 1)
          __builtin_amdgcn_s_sleep(4);
      }
      __syncthreads();
    }
  }
  // dispatch-end writeback publishes hseq to k_gemm_out (r12-r19 precedent)
}

// ---------------------------------------------------------------------------
// Kernel 3: Out = hseq[1..32] @ W_out.T + b_out   [fp16 MFMA, f32 out]
// r19 re-tiled body + COUNTED loop-top vmcnt: per-lane VMEM FIFO at loop top
// is [stage(s+1) x8 oldest, stores(s) x4 newest] -> vmcnt(4) completes the
// staging without draining the stores to HBM retirement (removes the
// ~600-1000 cyc/step store-drain bubble).  First iteration: vmcnt(0).
// ---------------------------------------------------------------------------
__global__ __launch_bounds__(512) void k_gemm_out(const unsigned short* __restrict__ hseq,
                                                  const float* __restrict__ Wout,
                                                  const float* __restrict__ bout,
                                                  float* __restrict__ out) {
  __shared__ __align__(16) unsigned short As[2][BB * HH];   // 2 x 64 KB
  const int tid = threadIdx.x;
  const int l = tid & 63;
  const int w = tid >> 6;
  const int wr = w >> 2;           // row-group 0/1 (32 rows)
  const int wc = w & 3;            // col-group 0..3 (32 cols)
  const int n00 = blockIdx.x * 128;
  const int bcol4 = (l >> 4) * 4;  // 4-float sub-col within a 16-col tile

  // preload TWO W_out col-tiles f32 -> f16 fragments in registers (once)
  const int kb = (l >> 4) * 8;
  uint4 w0r[2][16];
  float4 bo[2];
#pragma unroll
  for (int ct = 0; ct < 2; ++ct) {
    const int vr = n00 + wc * 32 + ct * 16 + (l & 15);
    bo[ct] = *(const float4*)(bout + n00 + wc * 32 + ct * 16 + bcol4);
#pragma unroll
    for (int kt = 0; kt < 16; ++kt) {
      const float* p = Wout + (size_t)vr * HH + kt * 32 + kb;
      float4 a = *(const float4*)p;
      float4 b = *(const float4*)(p + 4);
      __align__(16) unsigned short t8[8];
      t8[0] = f2h(a.x); t8[1] = f2h(a.y); t8[2] = f2h(a.z); t8[3] = f2h(a.w);
      t8[4] = f2h(b.x); t8[5] = f2h(b.y); t8[6] = f2h(b.z); t8[7] = f2h(b.w);
      w0r[ct][kt] = *(const uint4*)t8;
    }
  }

  // stage step 1 into As[0]
  const unsigned short* hs1 = hseq + (size_t)1 * (BB * HH);
#pragma unroll
  for (int it = 0; it < 8; ++it) {
    int ci = it * 512 + tid;
    int row = ci >> 6, cd = ci & 63;
    gload_lds16(hs1 + (size_t)row * HH + (cd ^ (row & 7)) * 8, As[0] + ci * 8);
  }

  int cur = 0;
  for (int s = 1; s <= TT; ++s) {
    if (s == 1)
      asm volatile("s_waitcnt vmcnt(0)" ::: "memory");   // stage(1): nothing else in flight
    else
      asm volatile("s_waitcnt vmcnt(4)" ::: "memory");   // stage done; 4 stores may drain
    __syncthreads();                                     // + prev reads of As[cur] done

    if (s < TT) {
      const unsigned short* hs = hseq + (size_t)(s + 1) * (BB * HH);
#pragma unroll
      for (int it = 0; it < 8; ++it) {
        int ci = it * 512 + tid;
        int row = ci >> 6, cd = ci & 63;
        gload_lds16(hs + (size_t)row * HH + (cd ^ (row & 7)) * 8, As[cur ^ 1] + ci * 8);
      }
    }

    const unsigned short* Ab = As[cur];
    f32x4 acc[2][2];   // [mg][ct]
#pragma unroll
    for (int mg = 0; mg < 2; ++mg)
#pragma unroll
      for (int ct = 0; ct < 2; ++ct) acc[mg][ct] = (f32x4){0.f, 0.f, 0.f, 0.f};

#pragma unroll
    for (int mg = 0; mg < 2; ++mg) {
      int row = wr * 32 + mg * 16 + (l & 15);
#pragma unroll
      for (int kt = 0; kt < 16; ++kt) {
        int c = kt * 4 + (l >> 4);
        f16x8 af = *(const f16x8*)&Ab[row * HH + (c ^ (row & 7)) * 8];
        // one af read feeds TWO MFMAs (col-tiles 0 and 1)
        acc[mg][0] = __builtin_amdgcn_mfma_f32_16x16x32_f16(
            __builtin_bit_cast(f16x8, w0r[0][kt]), af, acc[mg][0], 0, 0, 0);
        acc[mg][1] = __builtin_amdgcn_mfma_f32_16x16x32_f16(
            __builtin_bit_cast(f16x8, w0r[1][kt]), af, acc[mg][1], 0, 0, 0);
      }
    }

#pragma unroll
    for (int mg = 0; mg < 2; ++mg) {
      int b = wr * 32 + mg * 16 + (l & 15);
      float* orow = out + ((size_t)(b * TT + (s - 1))) * VV + n00 + wc * 32 + bcol4;
#pragma unroll
      for (int ct = 0; ct < 2; ++ct) {
        float4 v;
        v.x = acc[mg][ct][0] + bo[ct].x;
        v.y = acc[mg][ct][1] + bo[ct].y;
        v.z = acc[mg][ct][2] + bo[ct].z;
        v.w = acc[mg][ct][3] + bo[ct].w;
        *(float4*)(orow + ct * 16) = v;
      }
    }
    cur ^= 1;
  }
}

// ---------------------------------------------------------------------------
extern "C" void kernel_launch(void* const* d_in, const int* in_sizes, int n_in,
                              void* d_out, int out_size, void* d_ws, size_t ws_size,
                              hipStream_t stream) {
  const float* feat = (const float*)d_in[0];
  const int* cap = (const int*)d_in[1];
  // d_in[2] = seq_len (constant 32)
  const float* emb = (const float*)d_in[3];
  const float* Wih = (const float*)d_in[4];
  const float* Whh = (const float*)d_in[5];
  const float* bih = (const float*)d_in[6];
  const float* bhh = (const float*)d_in[7];
  const float* Wout = (const float*)d_in[8];
  const float* bout = (const float*)d_in[9];
  float* out = (float*)d_out;

  char* ws = (char*)d_ws;
  unsigned short* xseq = (unsigned short*)ws;                 //  2,162,688 (33 x 64 x 512 fp16)
  char* hseq = ws + 2162688;                                  //  2,162,688
  int* flags = (int*)(ws + 4325376);                          //      4,096

  hipMemsetAsync(flags, 0, 4096, stream);
  k_embed<<<dim3(2112), dim3(128), 0, stream>>>(feat, cap, emb, xseq);
  k_rnn<<<dim3(64), dim3(512), 0, stream>>>(xseq, Wih, Whh, bih, bhh, hseq, flags);
  k_gemm_out<<<dim3(250), dim3(512), 0, stream>>>((const unsigned short*)hseq, Wout, bout, out);
}

// Round 21
// 388.767 us; speedup vs baseline: 1.2545x; 1.0137x over previous
//
#include <hip/hip_runtime.h>
#include <stdint.h>

// Problem dims (fixed)
#define BB 64
#define TT 32
#define EE 512
#define HH 512
#define VV 32000
#define G4 2048

typedef _Float16 f16x8 __attribute__((ext_vector_type(8)));
typedef float f32x4 __attribute__((ext_vector_type(4)));

__device__ __forceinline__ unsigned short f2h(float f) {
  return __builtin_bit_cast(unsigned short, (_Float16)f);   // RNE hw cvt
}
__device__ __forceinline__ void gload_lds16(const unsigned short* g, unsigned short* l) {
  __builtin_amdgcn_global_load_lds((const __attribute__((address_space(1))) void*)g,
                                   (__attribute__((address_space(3))) void*)l, 16, 0, 0);
}
__device__ __forceinline__ float sigm(float x) { return 1.f / (1.f + __expf(-x)); }
__device__ __forceinline__ float tanh_fast(float x) {
  return 1.f - 2.f / (__expf(2.f * x) + 1.f);   // stable at +-inf
}

// ---------------------------------------------------------------------------
// Kernel 1: gather+cast x inputs -> fp16 xseq[33][64][512], 4 rows/block.
// Block 0 additionally zeroes the 64 rnn barrier flags (agent atomics, the
// proven transport) — replaces the separate hipMemsetAsync dispatch.
// ---------------------------------------------------------------------------
__global__ __launch_bounds__(128) void k_embed(const float* __restrict__ feat,
                                               const int* __restrict__ cap,
                                               const float* __restrict__ emb,
                                               unsigned short* __restrict__ xseq,
                                               int* __restrict__ flags) {
  if (blockIdx.x == 0 && threadIdx.x < 64)
    __hip_atomic_store(&flags[threadIdx.x], 0, __ATOMIC_RELAXED, __HIP_MEMORY_SCOPE_AGENT);

#pragma unroll
  for (int rr = 0; rr < 4; ++rr) {
    const int r = blockIdx.x * 4 + rr;  // 0..2111
    const int t = threadIdx.x;          // 128 thr x 4 f32
    const float* src;
    if (r < BB) {
      src = feat + (size_t)r * EE;
    } else {
      int p = r >> 6, b = r & 63;
      src = emb + (size_t)cap[b * TT + (p - 1)] * EE;
    }
    float4 v = ((const float4*)src)[t];
    ushort4 o;
    o.x = f2h(v.x); o.y = f2h(v.y); o.z = f2h(v.z); o.w = f2h(v.w);
    ((ushort4*)(xseq + (size_t)r * EE))[t] = o;
  }
}

// ---------------------------------------------------------------------------
// Kernel 2: persistent LSTM recurrence, K=1024 fused-input form, x-half
// hoisted into the barrier window.  (verbatim r18-r20 — passed, 286us)
// ---------------------------------------------------------------------------
__global__ __launch_bounds__(512) void k_rnn(const unsigned short* __restrict__ xseq,
                                             const float* __restrict__ Wih,
                                             const float* __restrict__ Whh,
                                             const float* __restrict__ bih,
                                             const float* __restrict__ bhh,
                                             char* hseq_base,
                                             int* __restrict__ flags) {
  __shared__ __align__(16) unsigned short W_lds[32 * 1024];  // fp16, 64 KB
  __shared__ float gate_buf[2048];                           // 8 KB
  unsigned short* hseq16 = (unsigned short*)hseq_base;
  unsigned int* hseq32 = (unsigned int*)hseq_base;

  const int tid = threadIdx.x;
  const int bid = blockIdx.x;
  const int u0 = bid * 8;
  const int l = tid & 63;
  const int w = tid >> 6;          // wave 0..7
  const int lr = l & 15;
  const int kc = l >> 4;           // 0..3
  const int nt = w & 1;            // n-tile (W'-row half: 0 = gates i,f; 1 = g,o)
  const int mt = w >> 1;           // m-tile (16-sample group)
  const int es = w * 8 + (l >> 3); // 0..63
  const int edu = l & 7;           // 0..7
  const int wrow = nt * 16 + lr;   // LDS W'-row this lane reads

  // ---- stage [W_ih | W_hh] (f32 -> fp16) into LDS, chunk-XOR swizzled ----
  {
    int row = tid >> 4;            // 0..31 (= g*8 + du)
    int sub = tid & 15;
    int g = row >> 3, du = row & 7;
    const float* pih = Wih + (size_t)(g * 512 + u0 + du) * EE;
    const float* phh = Whh + (size_t)(g * 512 + u0 + du) * HH;
#pragma unroll
    for (int c0 = 0; c0 < 8; ++c0) {
      int c = sub * 8 + c0;        // 16B-chunk index 0..127
      const float* src = (c < 64) ? (pih + c * 8) : (phh + (c - 64) * 8);
      float4 va = *(const float4*)src;
      float4 vb = *(const float4*)(src + 4);
      __align__(16) unsigned short t8[8];
      t8[0] = f2h(va.x); t8[1] = f2h(va.y); t8[2] = f2h(va.z); t8[3] = f2h(va.w);
      t8[4] = f2h(vb.x); t8[5] = f2h(vb.y); t8[6] = f2h(vb.z); t8[7] = f2h(vb.w);
      *(int4*)&W_lds[row * 1024 + ((c ^ (row & 7)) * 8)] = *(const int4*)t8;
    }
  }

  // ---- per-thread bias constants (step-invariant) ----
  float bsum[4];
#pragma unroll
  for (int g = 0; g < 4; ++g) {
    int n = g * 512 + u0 + edu;
    bsum[g] = bih[n] + bhh[n];
  }
  __syncthreads();   // W_lds staged before first MFMA

  const char* wbase = (const char*)W_lds + wrow * 2048;
  const size_t xoff = (size_t)(mt * 16 + lr) * EE + kc * 8;  // per-lane x/h offset

  // ---- prime step (p=0): gates = x0 @ W_ih.T + b  (h = c = 0) ----
  float c_reg;
  {
    f32x4 acc = {0.f, 0.f, 0.f, 0.f};
    const unsigned short* xb = xseq + xoff;
#pragma unroll
    for (int kk = 0; kk < 16; ++kk) {
      uint4 xq = *(const uint4*)(xb + kk * 32);
      int4 wq = *(const int4*)(wbase + (((kk * 4 + kc) ^ (wrow & 7)) * 16));
      acc = __builtin_amdgcn_mfma_f32_16x16x32_f16(
          __builtin_bit_cast(f16x8, xq), __builtin_bit_cast(f16x8, wq), acc, 0, 0, 0);
    }
    {
      int g = nt * 2 + (lr >> 3);
      int du = lr & 7;
#pragma unroll
      for (int j = 0; j < 4; ++j) {
        int ss = mt * 16 + kc * 4 + j;
        gate_buf[g * 512 + du * 64 + (ss ^ (du << 3))] = acc[j];
      }
    }
    __syncthreads();
    {
      float gi = gate_buf[0 * 512 + edu * 64 + (es ^ (edu << 3))] + bsum[0];
      float gg = gate_buf[2 * 512 + edu * 64 + (es ^ (edu << 3))] + bsum[2];
      float go = gate_buf[3 * 512 + edu * 64 + (es ^ (edu << 3))] + bsum[3];
      float cn = sigm(gi) * tanh_fast(gg);
      float hn = sigm(go) * tanh_fast(cn);
      c_reg = cn;
      unsigned int hb = f2h(hn);
      unsigned int other = (unsigned int)__shfl_xor((int)hb, 1);
      if (!(l & 1))
        __hip_atomic_store(&hseq32[(size_t)es * 256 + bid * 4 + (edu >> 1)],
                           hb | (other << 16), __ATOMIC_RELAXED, __HIP_MEMORY_SCOPE_AGENT);
    }
  }

  // arrive(1)
  asm volatile("s_waitcnt vmcnt(0)" ::: "memory");
  __syncthreads();
  if (tid == 0)
    __hip_atomic_store(&flags[bid], 1, __ATOMIC_RELAXED, __HIP_MEMORY_SCOPE_AGENT);

  // x-half for step 1 (overlaps peers' arrivals)
  f32x4 acca = {0.f, 0.f, 0.f, 0.f};
  {
    const unsigned short* xb = xseq + (size_t)1 * (BB * HH) + xoff;
#pragma unroll
    for (int kk = 0; kk < 16; ++kk) {
      uint4 xq = *(const uint4*)(xb + kk * 32);
      int4 wq = *(const int4*)(wbase + (((kk * 4 + kc) ^ (wrow & 7)) * 16));
      acca = __builtin_amdgcn_mfma_f32_16x16x32_f16(
          __builtin_bit_cast(f16x8, xq), __builtin_bit_cast(f16x8, wq), acca, 0, 0, 0);
    }
  }

  // wait(1)
  if (tid < 64) {
    while (__hip_atomic_load(&flags[tid], __ATOMIC_RELAXED, __HIP_MEMORY_SCOPE_AGENT) < 1)
      __builtin_amdgcn_s_sleep(4);
  }
  __syncthreads();

  // ---- 32 recurrent steps ----
  for (int s = 1; s <= TT; ++s) {
    const unsigned short* hb2 = hseq16 + (size_t)(s - 1) * (BB * HH) + xoff;
    f32x4 acc = acca;
#pragma unroll
    for (int kk = 0; kk < 16; ++kk) {
      uint4 hq = *(const uint4*)(hb2 + kk * 32);
      int4 wq = *(const int4*)(wbase + ((((kk + 16) * 4 + kc) ^ (wrow & 7)) * 16));
      acc = __builtin_amdgcn_mfma_f32_16x16x32_f16(
          __builtin_bit_cast(f16x8, hq), __builtin_bit_cast(f16x8, wq), acc, 0, 0, 0);
    }

    // gate partials -> LDS (XOR-swizzled on sample index)
    {
      int g = nt * 2 + (lr >> 3);
      int du = lr & 7;
#pragma unroll
      for (int j = 0; j < 4; ++j) {
        int ss = mt * 16 + kc * 4 + j;
        gate_buf[g * 512 + du * 64 + (ss ^ (du << 3))] = acc[j];
      }
    }
    __syncthreads();

    // epilogue: one (es, edu) update per thread
    {
      float gi = gate_buf[0 * 512 + edu * 64 + (es ^ (edu << 3))] + bsum[0];
      float gf = gate_buf[1 * 512 + edu * 64 + (es ^ (edu << 3))] + bsum[1];
      float gg = gate_buf[2 * 512 + edu * 64 + (es ^ (edu << 3))] + bsum[2];
      float go = gate_buf[3 * 512 + edu * 64 + (es ^ (edu << 3))] + bsum[3];
      float cn = sigm(gf) * c_reg + sigm(gi) * tanh_fast(gg);
      float hn = sigm(go) * tanh_fast(cn);
      c_reg = cn;
      unsigned int hb = f2h(hn);
      unsigned int other = (unsigned int)__shfl_xor((int)hb, 1);
      if (!(l & 1))
        __hip_atomic_store(&hseq32[(size_t)s * 16384 + es * 256 + bid * 4 + (edu >> 1)],
                           hb | (other << 16), __ATOMIC_RELAXED, __HIP_MEMORY_SCOPE_AGENT);
    }

    if (s < TT) {
      // arrive(s+1)
      asm volatile("s_waitcnt vmcnt(0)" ::: "memory");
      __syncthreads();
      if (tid == 0)
        __hip_atomic_store(&flags[bid], s + 1, __ATOMIC_RELAXED, __HIP_MEMORY_SCOPE_AGENT);

      // x-half for step s+1 (hidden under peers' arrival + poll window)
      acca = (f32x4){0.f, 0.f, 0.f, 0.f};
      const unsigned short* xb = xseq + (size_t)(s + 1) * (BB * HH) + xoff;
#pragma unroll
      for (int kk = 0; kk < 16; ++kk) {
        uint4 xq = *(const uint4*)(xb + kk * 32);
        int4 wq = *(const int4*)(wbase + (((kk * 4 + kc) ^ (wrow & 7)) * 16));
        acca = __builtin_amdgcn_mfma_f32_16x16x32_f16(
            __builtin_bit_cast(f16x8, xq), __builtin_bit_cast(f16x8, wq), acca, 0, 0, 0);
      }

      // wait(s+1)
      if (tid < 64) {
        while (__hip_atomic_load(&flags[tid], __ATOMIC_RELAXED, __HIP_MEMORY_SCOPE_AGENT) < s + 1)
          __builtin_amdgcn_s_sleep(4);
      }
      __syncthreads();
    }
  }
  // dispatch-end writeback publishes hseq to k_gemm_out (r12-r20 precedent)
}

// ---------------------------------------------------------------------------
// Kernel 3: Out = hseq[1..32] @ W_out.T + b_out   [fp16 MFMA, f32 out]
// (verbatim r20 — re-tiled 2x4 waves, W in regs, dbuf staging, counted vmcnt)
// ---------------------------------------------------------------------------
__global__ __launch_bounds__(512) void k_gemm_out(const unsigned short* __restrict__ hseq,
                                                  const float* __restrict__ Wout,
                                                  const float* __restrict__ bout,
                                                  float* __restrict__ out) {
  __shared__ __align__(16) unsigned short As[2][BB * HH];   // 2 x 64 KB
  const int tid = threadIdx.x;
  const int l = tid & 63;
  const int w = tid >> 6;
  const int wr = w >> 2;           // row-group 0/1 (32 rows)
  const int wc = w & 3;            // col-group 0..3 (32 cols)
  const int n00 = blockIdx.x * 128;
  const int bcol4 = (l >> 4) * 4;  // 4-float sub-col within a 16-col tile

  // preload TWO W_out col-tiles f32 -> f16 fragments in registers (once)
  const int kb = (l >> 4) * 8;
  uint4 w0r[2][16];
  float4 bo[2];
#pragma unroll
  for (int ct = 0; ct < 2; ++ct) {
    const int vr = n00 + wc * 32 + ct * 16 + (l & 15);
    bo[ct] = *(const float4*)(bout + n00 + wc * 32 + ct * 16 + bcol4);
#pragma unroll
    for (int kt = 0; kt < 16; ++kt) {
      const float* p = Wout + (size_t)vr * HH + kt * 32 + kb;
      float4 a = *(const float4*)p;
      float4 b = *(const float4*)(p + 4);
      __align__(16) unsigned short t8[8];
      t8[0] = f2h(a.x); t8[1] = f2h(a.y); t8[2] = f2h(a.z); t8[3] = f2h(a.w);
      t8[4] = f2h(b.x); t8[5] = f2h(b.y); t8[6] = f2h(b.z); t8[7] = f2h(b.w);
      w0r[ct][kt] = *(const uint4*)t8;
    }
  }

  // stage step 1 into As[0]
  const unsigned short* hs1 = hseq + (size_t)1 * (BB * HH);
#pragma unroll
  for (int it = 0; it < 8; ++it) {
    int ci = it * 512 + tid;
    int row = ci >> 6, cd = ci & 63;
    gload_lds16(hs1 + (size_t)row * HH + (cd ^ (row & 7)) * 8, As[0] + ci * 8);
  }

  int cur = 0;
  for (int s = 1; s <= TT; ++s) {
    if (s == 1)
      asm volatile("s_waitcnt vmcnt(0)" ::: "memory");   // stage(1): nothing else in flight
    else
      asm volatile("s_waitcnt vmcnt(4)" ::: "memory");   // stage done; 4 stores may drain
    __syncthreads();                                     // + prev reads of As[cur] done

    if (s < TT) {
      const unsigned short* hs = hseq + (size_t)(s + 1) * (BB * HH);
#pragma unroll
      for (int it = 0; it < 8; ++it) {
        int ci = it * 512 + tid;
        int row = ci >> 6, cd = ci & 63;
        gload_lds16(hs + (size_t)row * HH + (cd ^ (row & 7)) * 8, As[cur ^ 1] + ci * 8);
      }
    }

    const unsigned short* Ab = As[cur];
    f32x4 acc[2][2];   // [mg][ct]
#pragma unroll
    for (int mg = 0; mg < 2; ++mg)
#pragma unroll
      for (int ct = 0; ct < 2; ++ct) acc[mg][ct] = (f32x4){0.f, 0.f, 0.f, 0.f};

#pragma unroll
    for (int mg = 0; mg < 2; ++mg) {
      int row = wr * 32 + mg * 16 + (l & 15);
#pragma unroll
      for (int kt = 0; kt < 16; ++kt) {
        int c = kt * 4 + (l >> 4);
        f16x8 af = *(const f16x8*)&Ab[row * HH + (c ^ (row & 7)) * 8];
        // one af read feeds TWO MFMAs (col-tiles 0 and 1)
        acc[mg][0] = __builtin_amdgcn_mfma_f32_16x16x32_f16(
            __builtin_bit_cast(f16x8, w0r[0][kt]), af, acc[mg][0], 0, 0, 0);
        acc[mg][1] = __builtin_amdgcn_mfma_f32_16x16x32_f16(
            __builtin_bit_cast(f16x8, w0r[1][kt]), af, acc[mg][1], 0, 0, 0);
      }
    }

#pragma unroll
    for (int mg = 0; mg < 2; ++mg) {
      int b = wr * 32 + mg * 16 + (l & 15);
      float* orow = out + ((size_t)(b * TT + (s - 1))) * VV + n00 + wc * 32 + bcol4;
#pragma unroll
      for (int ct = 0; ct < 2; ++ct) {
        float4 v;
        v.x = acc[mg][ct][0] + bo[ct].x;
        v.y = acc[mg][ct][1] + bo[ct].y;
        v.z = acc[mg][ct][2] + bo[ct].z;
        v.w = acc[mg][ct][3] + bo[ct].w;
        *(float4*)(orow + ct * 16) = v;
      }
    }
    cur ^= 1;
  }
}

// ---------------------------------------------------------------------------
extern "C" void kernel_launch(void* const* d_in, const int* in_sizes, int n_in,
                              void* d_out, int out_size, void* d_ws, size_t ws_size,
                              hipStream_t stream) {
  const float* feat = (const float*)d_in[0];
  const int* cap = (const int*)d_in[1];
  // d_in[2] = seq_len (constant 32)
  const float* emb = (const float*)d_in[3];
  const float* Wih = (const float*)d_in[4];
  const float* Whh = (const float*)d_in[5];
  const float* bih = (const float*)d_in[6];
  const float* bhh = (const float*)d_in[7];
  const float* Wout = (const float*)d_in[8];
  const float* bout = (const float*)d_in[9];
  float* out = (float*)d_out;

  char* ws = (char*)d_ws;
  unsigned short* xseq = (unsigned short*)ws;                 //  2,162,688 (33 x 64 x 512 fp16)
  char* hseq = ws + 2162688;                                  //  2,162,688
  int* flags = (int*)(ws + 4325376);                          //      4,096

  k_embed<<<dim3(528), dim3(128), 0, stream>>>(feat, cap, emb, xseq, flags);
  k_rnn<<<dim3(64), dim3(512), 0, stream>>>(xseq, Wih, Whh, bih, bhh, hseq, flags);
  k_gemm_out<<<dim3(250), dim3(512), 0, stream>>>((const unsigned short*)hseq, Wout, bout, out);
}